// Round 3
// baseline (2713.747 us; speedup 1.0000x reference)
//
#include <hip/hip_runtime.h>

typedef unsigned short u16;
typedef unsigned int u32;
typedef __attribute__((ext_vector_type(8))) short short8;
typedef __attribute__((ext_vector_type(4))) short short4_t;
typedef __attribute__((ext_vector_type(4))) float f32x4;
typedef const __attribute__((address_space(1))) u32 gu32;
typedef __attribute__((address_space(3))) u32 lu32;

#define NGRID 256
#define BDIM 512

__device__ inline u16 f2bf(float f){
  unsigned u = __float_as_uint(f);
  return (u16)((u + 0x7FFFu + ((u>>16)&1u)) >> 16);
}
__device__ inline float bf2f(u16 h){ return __uint_as_float(((unsigned)h)<<16); }
__device__ inline void splitw(float f, u16 &hi, u16 &lo){
  hi = f2bf(f);
  lo = f2bf(f - bf2f(hi));
}
__device__ inline void gll16(const void* g, void* l){
  __builtin_amdgcn_global_load_lds((gu32*)g, (lu32*)l, 16, 0, 0);
}

// W[k][n] (1024x1024 row-major) -> Wth/Wtl[n][k] bf16 hi/lo, tiled transpose.
__global__ __launch_bounds__(256) void prep_weights(const float* __restrict__ W,
                                                    u16* __restrict__ Wth, u16* __restrict__ Wtl){
  __shared__ float tile[32][33];
  int n0 = blockIdx.x*32, k0 = blockIdx.y*32;
  int tx = threadIdx.x & 31, ty = threadIdx.x >> 5;  // 32 x 8
  #pragma unroll
  for (int j=0;j<4;++j)
    tile[ty+8*j][tx] = W[(k0+ty+8*j)*1024 + n0 + tx];
  __syncthreads();
  #pragma unroll
  for (int j=0;j<4;++j){
    int nl = ty + 8*j;
    float f = tile[tx][nl];
    u16 hi, lo; splitw(f, hi, lo);
    Wth[(size_t)(n0+nl)*1024 + k0 + tx] = hi;
    Wtl[(size_t)(n0+nl)*1024 + k0 + tx] = lo;
  }
}

__global__ __launch_bounds__(256) void init_z(const float* __restrict__ zi, float* __restrict__ z,
                                              u16* __restrict__ zh, u16* __restrict__ zl){
  int i = blockIdx.x*256 + threadIdx.x;
  float f = zi[i];
  z[i] = f;
  u16 h,l; splitw(f,h,l);
  zh[i]=h; zl[i]=l;
}

// Block tile BM=32 x BN=64, BK=128 x 8 K-steps, double-buffered global_load_lds.
// 8 waves = nr(2 col-halves) x kq(4 K-quarters); wave tile 32x32 (M_rep=2,N_rep=2),
// k-split-4 in-block, LDS tree-reduction in epilogue.
// LDS stage buf (bytes): Ahi [0,8K) Alo [8K,16K) Bhi [16K,32K) Blo [32K,48K)
// MODE 0: h = tanh(A@W1 + ti*wt + b1); MODE 1+s: k = A@W2 + b2 + RK4 stage-s.
template<int MODE>
__global__ __launch_bounds__(512) void fused_gemm(
    const u16* __restrict__ Ahi, const u16* __restrict__ Alo,   // [512][1024]
    const u16* __restrict__ Wth, const u16* __restrict__ Wtl,   // [1024][1024] (n-major)
    const float* __restrict__ bias, const float* __restrict__ wtv,
    const float* __restrict__ tvec, int step, int which,
    u16* __restrict__ OutHi, u16* __restrict__ OutLo,
    float* __restrict__ Zbuf, float* __restrict__ Zacc)
{
  __shared__ u16 stg[2][24576];          // 2 x 48 KB
  __shared__ float red[4][32][68];       // kq partials, padded (+4) for banks
  const int tid  = threadIdx.x;
  const int b    = blockIdx.x;
  const int cb   = b & 15, rbk = b >> 4;     // col-block(64) [XCD-pinned cb%8] x row-block(32)
  const int wave = tid >> 6, lane = tid & 63;
  const int nr   = wave & 1, kq = wave >> 1;
  const int lr   = lane & 15, ks = lane >> 4;

  // ---- staging addresses (chunk = 16B = 8 u16 along k; src pre-swizzled, dest linear) ----
  const int ra = tid >> 4, ca = tid & 15, sa = ca ^ (ra & 7);
  const size_t aoff_g = (size_t)(rbk*32 + ra)*1024 + sa*8;
  const int qb1 = 512 + tid;
  const int rb0 = tid >> 4, cb0_ = tid & 15, sb0 = cb0_ ^ (rb0 & 7);
  const int rb1 = qb1 >> 4, cb1_ = qb1 & 15, sb1 = cb1_ ^ (rb1 & 7);
  const size_t boff0_g = (size_t)(cb*64 + rb0)*1024 + sb0*8;
  const size_t boff1_g = (size_t)(cb*64 + rb1)*1024 + sb1*8;
  const int wbase = (tid & ~63) * 16;        // wave-uniform LDS byte base

  auto STAGE = [&](int bufi, int kt){
    char* L = (char*)&stg[bufi][0];
    const size_t ko = (size_t)kt * 128;
    gll16(Ahi + aoff_g + ko, L + wbase);
    gll16(Alo + aoff_g + ko, L + 8192 + wbase);
    gll16(Wth + boff0_g + ko, L + 16384 + wbase);
    gll16(Wth + boff1_g + ko, L + 24576 + wbase);
    gll16(Wtl + boff0_g + ko, L + 32768 + wbase);
    gll16(Wtl + boff1_g + ko, L + 40960 + wbase);
  };

  // ---- fragment read offsets: row r byte r*256, logical chunk (kq*4+ks) ^ (r&7) ----
  const int ci = ((kq*4 + ks) ^ (lr & 7)) * 16;
  const int arow = lr*256 + ci;
  const int brow = nr*8192 + lr*256 + ci;

  f32x4 a00={0.f,0.f,0.f,0.f}, a01=a00, a10=a00, a11=a00;

  STAGE(0, 0);
  __syncthreads();
  #pragma unroll
  for (int kt = 0; kt < 8; ++kt){
    const int cur = kt & 1;
    if (kt < 7) STAGE(cur ^ 1, kt + 1);
    const char* L = (const char*)&stg[cur][0];
    short8 ah0 = *(const short8*)(L + arow);
    short8 ah1 = *(const short8*)(L + 4096 + arow);
    short8 al0 = *(const short8*)(L + 8192 + arow);
    short8 al1 = *(const short8*)(L + 12288 + arow);
    short8 bh0 = *(const short8*)(L + 16384 + brow);
    short8 bh1 = *(const short8*)(L + 20480 + brow);
    short8 bl0 = *(const short8*)(L + 32768 + brow);
    short8 bl1 = *(const short8*)(L + 36864 + brow);
    a00 = __builtin_amdgcn_mfma_f32_16x16x32_bf16(ah0, bh0, a00, 0,0,0);
    a01 = __builtin_amdgcn_mfma_f32_16x16x32_bf16(ah0, bh1, a01, 0,0,0);
    a10 = __builtin_amdgcn_mfma_f32_16x16x32_bf16(ah1, bh0, a10, 0,0,0);
    a11 = __builtin_amdgcn_mfma_f32_16x16x32_bf16(ah1, bh1, a11, 0,0,0);
    a00 = __builtin_amdgcn_mfma_f32_16x16x32_bf16(al0, bh0, a00, 0,0,0);
    a01 = __builtin_amdgcn_mfma_f32_16x16x32_bf16(al0, bh1, a01, 0,0,0);
    a10 = __builtin_amdgcn_mfma_f32_16x16x32_bf16(al1, bh0, a10, 0,0,0);
    a11 = __builtin_amdgcn_mfma_f32_16x16x32_bf16(al1, bh1, a11, 0,0,0);
    a00 = __builtin_amdgcn_mfma_f32_16x16x32_bf16(ah0, bl0, a00, 0,0,0);
    a01 = __builtin_amdgcn_mfma_f32_16x16x32_bf16(ah0, bl1, a01, 0,0,0);
    a10 = __builtin_amdgcn_mfma_f32_16x16x32_bf16(ah1, bl0, a10, 0,0,0);
    a11 = __builtin_amdgcn_mfma_f32_16x16x32_bf16(ah1, bl1, a11, 0,0,0);
    __syncthreads();
  }

  // ---- deposit kq-partials (C/D: col=lane&15, row=(lane>>4)*4+i  [m89]) ----
  #pragma unroll
  for (int i=0;i<4;++i){
    red[kq][ks*4 + i][nr*32 + lr]      = a00[i];
    red[kq][ks*4 + i][nr*32 + 16 + lr] = a01[i];
    red[kq][16 + ks*4 + i][nr*32 + lr]      = a10[i];
    red[kq][16 + ks*4 + i][nr*32 + 16 + lr] = a11[i];
  }
  __syncthreads();

  // ---- reduce + fused epilogue: thread -> (row r, cols c4..c4+3) ----
  const int r = tid >> 4, c4 = (tid & 15) * 4;
  f32x4 s = *(const f32x4*)&red[0][r][c4];
  s += *(const f32x4*)&red[1][r][c4];
  s += *(const f32x4*)&red[2][r][c4];
  s += *(const f32x4*)&red[3][r][c4];

  const float t0 = tvec[step], t1 = tvec[step+1];
  const float dt = t1 - t0, half = 0.5f*dt;
  const int colb = cb*64 + c4;
  const size_t idx = (size_t)(rbk*32 + r)*1024 + colb;
  const f32x4 bb = *(const f32x4*)&bias[colb];

  short4_t oh, ol;
  if constexpr (MODE == 0){
    const float ti = (which == 0) ? t0 : ((which == 3) ? t1 : (t0 + half));
    const f32x4 wv = *(const f32x4*)&wtv[colb];
    #pragma unroll
    for (int j=0;j<4;++j){
      float hv = tanhf(s[j] + bb[j] + ti*wv[j]);
      u16 h,l; splitw(hv,h,l);
      oh[j] = (short)h; ol[j] = (short)l;
    }
  } else {
    constexpr int S = MODE - 1;
    const float dt6 = dt*(1.0f/6.0f), dt3 = dt*(1.0f/3.0f);
    const f32x4 kv = s + bb;
    f32x4 zm;
    if constexpr (S == 0){
      const f32x4 zv = *(const f32x4*)&Zbuf[idx];
      zm = zv + half*kv;
      *(f32x4*)&Zacc[idx] = zv + dt6*kv;
    } else if constexpr (S == 1){
      zm = *(const f32x4*)&Zbuf[idx] + half*kv;
      *(f32x4*)&Zacc[idx] = *(const f32x4*)&Zacc[idx] + dt3*kv;
    } else if constexpr (S == 2){
      zm = *(const f32x4*)&Zbuf[idx] + dt*kv;
      *(f32x4*)&Zacc[idx] = *(const f32x4*)&Zacc[idx] + dt3*kv;
    } else {
      zm = *(const f32x4*)&Zacc[idx] + dt6*kv;
      *(f32x4*)&Zbuf[idx] = zm;                // z (== d_out)
    }
    #pragma unroll
    for (int j=0;j<4;++j){
      u16 h,l; splitw(zm[j],h,l);
      oh[j] = (short)h; ol[j] = (short)l;
    }
  }
  *(short4_t*)&OutHi[idx] = oh;
  *(short4_t*)&OutLo[idx] = ol;
}

extern "C" void kernel_launch(void* const* d_in, const int* in_sizes, int n_in,
                              void* d_out, int out_size, void* d_ws, size_t ws_size,
                              hipStream_t stream)
{
  (void)in_sizes; (void)n_in; (void)out_size; (void)ws_size;
  const float* z_init = (const float*)d_in[0];
  const float* tvec   = (const float*)d_in[1];
  const float* W1     = (const float*)d_in[2];
  const float* b1     = (const float*)d_in[3];
  const float* wt     = (const float*)d_in[4];
  const float* W2     = (const float*)d_in[5];
  const float* b2     = (const float*)d_in[6];
  float* z = (float*)d_out;                    // fp32 master state lives in d_out

  char* p = (char*)d_ws;
  const size_t EL = 512*1024;
  u16* zh  = (u16*)p; p += EL*2;
  u16* zl  = (u16*)p; p += EL*2;
  u16* zmh = (u16*)p; p += EL*2;
  u16* zml = (u16*)p; p += EL*2;
  u16* hh  = (u16*)p; p += EL*2;
  u16* hl  = (u16*)p; p += EL*2;
  float* zacc = (float*)p; p += EL*4;
  u16* W1h = (u16*)p; p += (size_t)1024*1024*2;
  u16* W1l = (u16*)p; p += (size_t)1024*1024*2;
  u16* W2h = (u16*)p; p += (size_t)1024*1024*2;
  u16* W2l = (u16*)p; p += (size_t)1024*1024*2;

  prep_weights<<<dim3(32,32),256,0,stream>>>(W1, W1h, W1l);
  prep_weights<<<dim3(32,32),256,0,stream>>>(W2, W2h, W2l);
  init_z<<<2048,256,0,stream>>>(z_init, z, zh, zl);

  for (int step=0; step<32; ++step){
    for (int s=0; s<4; ++s){
      const u16* ah = (s==0)? zh : zmh;
      const u16* al = (s==0)? zl : zml;
      fused_gemm<0><<<NGRID,BDIM,0,stream>>>(ah, al, W1h, W1l, b1, wt, tvec, step, s,
                                             hh, hl, nullptr, nullptr);
      u16* oh = (s==3)? zh : zmh;
      u16* ol = (s==3)? zl : zml;
      switch (s){
        case 0: fused_gemm<1><<<NGRID,BDIM,0,stream>>>(hh, hl, W2h, W2l, b2, nullptr, tvec, step, s, oh, ol, z, zacc); break;
        case 1: fused_gemm<2><<<NGRID,BDIM,0,stream>>>(hh, hl, W2h, W2l, b2, nullptr, tvec, step, s, oh, ol, z, zacc); break;
        case 2: fused_gemm<3><<<NGRID,BDIM,0,stream>>>(hh, hl, W2h, W2l, b2, nullptr, tvec, step, s, oh, ol, z, zacc); break;
        case 3: fused_gemm<4><<<NGRID,BDIM,0,stream>>>(hh, hl, W2h, W2l, b2, nullptr, tvec, step, s, oh, ol, z, zacc); break;
      }
    }
  }
}

// Round 4
// 2245.550 us; speedup vs baseline: 1.2085x; 1.2085x over previous
//
#include <hip/hip_runtime.h>

typedef unsigned short u16;
typedef unsigned int u32;
typedef __attribute__((ext_vector_type(8))) short short8;
typedef __attribute__((ext_vector_type(4))) short short4_t;
typedef __attribute__((ext_vector_type(4))) float f32x4;
typedef const __attribute__((address_space(1))) u32 gu32;
typedef __attribute__((address_space(3))) u32 lu32;

#define NGRID 512
#define BDIM 256

__device__ inline u16 f2bf(float f){
  unsigned u = __float_as_uint(f);
  return (u16)((u + 0x7FFFu + ((u>>16)&1u)) >> 16);
}
__device__ inline float bf2f(u16 h){ return __uint_as_float(((unsigned)h)<<16); }
__device__ inline void splitw(float f, u16 &hi, u16 &lo){
  hi = f2bf(f);
  lo = f2bf(f - bf2f(hi));
}
__device__ inline void gll16(const void* g, void* l){
  __builtin_amdgcn_global_load_lds((gu32*)g, (lu32*)l, 16, 0, 0);
}

// W[k][n] (1024x1024 row-major) -> Wth/Wtl[n][k] bf16 hi/lo, tiled transpose.
__global__ __launch_bounds__(256) void prep_weights(const float* __restrict__ W,
                                                    u16* __restrict__ Wth, u16* __restrict__ Wtl){
  __shared__ float tile[32][33];
  int n0 = blockIdx.x*32, k0 = blockIdx.y*32;
  int tx = threadIdx.x & 31, ty = threadIdx.x >> 5;  // 32 x 8
  #pragma unroll
  for (int j=0;j<4;++j)
    tile[ty+8*j][tx] = W[(k0+ty+8*j)*1024 + n0 + tx];
  __syncthreads();
  #pragma unroll
  for (int j=0;j<4;++j){
    int nl = ty + 8*j;
    float f = tile[tx][nl];
    u16 hi, lo; splitw(f, hi, lo);
    Wth[(size_t)(n0+nl)*1024 + k0 + tx] = hi;
    Wtl[(size_t)(n0+nl)*1024 + k0 + tx] = lo;
  }
}

__global__ __launch_bounds__(256) void init_z(const float* __restrict__ zi, float* __restrict__ z,
                                              u16* __restrict__ zh, u16* __restrict__ zl){
  int i = blockIdx.x*256 + threadIdx.x;
  float f = zi[i];
  z[i] = f;
  u16 h,l; splitw(f,h,l);
  zh[i]=h; zl[i]=l;
}

// Block tile 32x32, BK=128 x 8 K-steps, dbuf global_load_lds staging, 256 thr.
// 4 waves = kq-split-4: each wave computes full 32x32 for its K-quarter
// (M_rep=2,N_rep=2, 12 MFMA : 8 ds_read_b128 per K-step), LDS reduction after.
// LDS = 64KB total: stage 2x32KB; reduction [4][32][36] f32 ALIASES stage
// (used only after final K-step barrier). -> 2 blocks/CU for cross-block
// overlap of the vmcnt(0) barrier drains.
// Stage buf layout (bytes): Ahi [0,8K) Alo [8K,16K) Bhi [16K,24K) Blo [24K,32K)
// MODE 0: h = tanh(A@W1 + ti*wt + b1); MODE 1+s: k = A@W2 + b2 + RK4 stage-s.
template<int MODE>
__global__ __launch_bounds__(256, 2) void fused_gemm(
    const u16* __restrict__ Ahi, const u16* __restrict__ Alo,   // [512][1024]
    const u16* __restrict__ Wth, const u16* __restrict__ Wtl,   // [1024][1024] (n-major)
    const float* __restrict__ bias, const float* __restrict__ wtv,
    const float* __restrict__ tvec, int step, int which,
    u16* __restrict__ OutHi, u16* __restrict__ OutLo,
    float* __restrict__ Zbuf, float* __restrict__ Zacc)
{
  __shared__ char Lraw[65536];           // stage 2x32KB; red aliases [0,18432)
  float* red = (float*)Lraw;             // [4][32][36] after K-loop
  const int tid  = threadIdx.x;
  const int b    = blockIdx.x;
  const int cb   = b & 31, rbk = b >> 5; // col-block(32) [XCD-pinned cb%8] x row-block(32)
  const int kq   = tid >> 6, lane = tid & 63;
  const int lr   = lane & 15, ks = lane >> 4;

  // ---- staging (chunk = 16B = 8 u16 along k; linear LDS dest, pre-swizzled src) ----
  const int r0 = tid >> 4,        cc0 = tid & 15, s0 = cc0 ^ (r0 & 7);
  const int t1 = tid + 256;
  const int r1 = t1 >> 4,         cc1 = t1 & 15,  s1 = cc1 ^ (r1 & 7);
  const size_t a0 = (size_t)(rbk*32 + r0)*1024 + s0*8;
  const size_t a1 = (size_t)(rbk*32 + r1)*1024 + s1*8;
  const size_t b0 = (size_t)(cb*32 + r0)*1024 + s0*8;
  const size_t b1 = (size_t)(cb*32 + r1)*1024 + s1*8;
  const int wb0 = (tid & ~63) * 16;      // wave-uniform LDS byte base, chunk-set 0
  const int wb1 = 4096 + wb0;            // chunk-set 1

  auto STAGE = [&](int bufi, int kt){
    char* L = Lraw + bufi*32768;
    const size_t ko = (size_t)kt * 128;
    gll16(Ahi + a0 + ko, L + wb0);
    gll16(Ahi + a1 + ko, L + wb1);
    gll16(Alo + a0 + ko, L + 8192 + wb0);
    gll16(Alo + a1 + ko, L + 8192 + wb1);
    gll16(Wth + b0 + ko, L + 16384 + wb0);
    gll16(Wth + b1 + ko, L + 16384 + wb1);
    gll16(Wtl + b0 + ko, L + 24576 + wb0);
    gll16(Wtl + b1 + ko, L + 24576 + wb1);
  };

  // ---- fragment reads: row r at byte r*256, logical chunk (kq*4+ks) ^ (r&7) ----
  const int ci = ((kq*4 + ks) ^ (lr & 7)) * 16;
  const int ro = lr*256 + ci;            // shared by A rows (lr) and B cols (lr)

  f32x4 a00={0.f,0.f,0.f,0.f}, a01=a00, a10=a00, a11=a00;

  STAGE(0, 0);
  __syncthreads();
  #pragma unroll
  for (int kt = 0; kt < 8; ++kt){
    const int cur = kt & 1;
    if (kt < 7) STAGE(cur ^ 1, kt + 1);
    const char* L = Lraw + cur*32768;
    short8 ah0 = *(const short8*)(L + ro);
    short8 ah1 = *(const short8*)(L + 4096  + ro);
    short8 al0 = *(const short8*)(L + 8192  + ro);
    short8 al1 = *(const short8*)(L + 12288 + ro);
    short8 bh0 = *(const short8*)(L + 16384 + ro);
    short8 bh1 = *(const short8*)(L + 20480 + ro);
    short8 bl0 = *(const short8*)(L + 24576 + ro);
    short8 bl1 = *(const short8*)(L + 28672 + ro);
    a00 = __builtin_amdgcn_mfma_f32_16x16x32_bf16(ah0, bh0, a00, 0,0,0);
    a01 = __builtin_amdgcn_mfma_f32_16x16x32_bf16(ah0, bh1, a01, 0,0,0);
    a10 = __builtin_amdgcn_mfma_f32_16x16x32_bf16(ah1, bh0, a10, 0,0,0);
    a11 = __builtin_amdgcn_mfma_f32_16x16x32_bf16(ah1, bh1, a11, 0,0,0);
    a00 = __builtin_amdgcn_mfma_f32_16x16x32_bf16(al0, bh0, a00, 0,0,0);
    a01 = __builtin_amdgcn_mfma_f32_16x16x32_bf16(al0, bh1, a01, 0,0,0);
    a10 = __builtin_amdgcn_mfma_f32_16x16x32_bf16(al1, bh0, a10, 0,0,0);
    a11 = __builtin_amdgcn_mfma_f32_16x16x32_bf16(al1, bh1, a11, 0,0,0);
    a00 = __builtin_amdgcn_mfma_f32_16x16x32_bf16(ah0, bl0, a00, 0,0,0);
    a01 = __builtin_amdgcn_mfma_f32_16x16x32_bf16(ah0, bl1, a01, 0,0,0);
    a10 = __builtin_amdgcn_mfma_f32_16x16x32_bf16(ah1, bl0, a10, 0,0,0);
    a11 = __builtin_amdgcn_mfma_f32_16x16x32_bf16(ah1, bl1, a11, 0,0,0);
    __syncthreads();
  }

  // ---- deposit kq-partials into aliased red[4][32][36] (stage no longer read) ----
  // C/D: col=lane&15, row=(lane>>4)*4+i  [m89]
  #pragma unroll
  for (int i=0;i<4;++i){
    red[(kq*32 + ks*4 + i)*36 + lr]           = a00[i];
    red[(kq*32 + ks*4 + i)*36 + 16 + lr]      = a01[i];
    red[(kq*32 + 16 + ks*4 + i)*36 + lr]      = a10[i];
    red[(kq*32 + 16 + ks*4 + i)*36 + 16 + lr] = a11[i];
  }
  __syncthreads();

  // ---- reduce + fused epilogue: thread -> (row rr, cols c4..c4+3) ----
  const int rr = tid >> 3, c4 = (tid & 7) * 4;
  f32x4 s = *(const f32x4*)&red[(0*32 + rr)*36 + c4];
  s += *(const f32x4*)&red[(1*32 + rr)*36 + c4];
  s += *(const f32x4*)&red[(2*32 + rr)*36 + c4];
  s += *(const f32x4*)&red[(3*32 + rr)*36 + c4];

  const float t0 = tvec[step], t1v = tvec[step+1];
  const float dt = t1v - t0, half = 0.5f*dt;
  const int colb = cb*32 + c4;
  const size_t idx = (size_t)(rbk*32 + rr)*1024 + colb;
  const f32x4 bb = *(const f32x4*)&bias[colb];

  short4_t oh, ol;
  if constexpr (MODE == 0){
    const float ti = (which == 0) ? t0 : ((which == 3) ? t1v : (t0 + half));
    const f32x4 wv = *(const f32x4*)&wtv[colb];
    #pragma unroll
    for (int j=0;j<4;++j){
      float hv = tanhf(s[j] + bb[j] + ti*wv[j]);
      u16 h,l; splitw(hv,h,l);
      oh[j] = (short)h; ol[j] = (short)l;
    }
  } else {
    constexpr int S = MODE - 1;
    const float dt6 = dt*(1.0f/6.0f), dt3 = dt*(1.0f/3.0f);
    const f32x4 kv = s + bb;
    f32x4 zm;
    if constexpr (S == 0){
      const f32x4 zv = *(const f32x4*)&Zbuf[idx];
      zm = zv + half*kv;
      *(f32x4*)&Zacc[idx] = zv + dt6*kv;
    } else if constexpr (S == 1){
      zm = *(const f32x4*)&Zbuf[idx] + half*kv;
      *(f32x4*)&Zacc[idx] = *(const f32x4*)&Zacc[idx] + dt3*kv;
    } else if constexpr (S == 2){
      zm = *(const f32x4*)&Zbuf[idx] + dt*kv;
      *(f32x4*)&Zacc[idx] = *(const f32x4*)&Zacc[idx] + dt3*kv;
    } else {
      zm = *(const f32x4*)&Zacc[idx] + dt6*kv;
      *(f32x4*)&Zbuf[idx] = zm;                // z (== d_out)
    }
    #pragma unroll
    for (int j=0;j<4;++j){
      u16 h,l; splitw(zm[j],h,l);
      oh[j] = (short)h; ol[j] = (short)l;
    }
  }
  *(short4_t*)&OutHi[idx] = oh;
  *(short4_t*)&OutLo[idx] = ol;
}

extern "C" void kernel_launch(void* const* d_in, const int* in_sizes, int n_in,
                              void* d_out, int out_size, void* d_ws, size_t ws_size,
                              hipStream_t stream)
{
  (void)in_sizes; (void)n_in; (void)out_size; (void)ws_size;
  const float* z_init = (const float*)d_in[0];
  const float* tvec   = (const float*)d_in[1];
  const float* W1     = (const float*)d_in[2];
  const float* b1     = (const float*)d_in[3];
  const float* wt     = (const float*)d_in[4];
  const float* W2     = (const float*)d_in[5];
  const float* b2     = (const float*)d_in[6];
  float* z = (float*)d_out;                    // fp32 master state lives in d_out

  char* p = (char*)d_ws;
  const size_t EL = 512*1024;
  u16* zh  = (u16*)p; p += EL*2;
  u16* zl  = (u16*)p; p += EL*2;
  u16* zmh = (u16*)p; p += EL*2;
  u16* zml = (u16*)p; p += EL*2;
  u16* hh  = (u16*)p; p += EL*2;
  u16* hl  = (u16*)p; p += EL*2;
  float* zacc = (float*)p; p += EL*4;
  u16* W1h = (u16*)p; p += (size_t)1024*1024*2;
  u16* W1l = (u16*)p; p += (size_t)1024*1024*2;
  u16* W2h = (u16*)p; p += (size_t)1024*1024*2;
  u16* W2l = (u16*)p; p += (size_t)1024*1024*2;

  prep_weights<<<dim3(32,32),256,0,stream>>>(W1, W1h, W1l);
  prep_weights<<<dim3(32,32),256,0,stream>>>(W2, W2h, W2l);
  init_z<<<2048,256,0,stream>>>(z_init, z, zh, zl);

  for (int step=0; step<32; ++step){
    for (int s=0; s<4; ++s){
      const u16* ah = (s==0)? zh : zmh;
      const u16* al = (s==0)? zl : zml;
      fused_gemm<0><<<NGRID,BDIM,0,stream>>>(ah, al, W1h, W1l, b1, wt, tvec, step, s,
                                             hh, hl, nullptr, nullptr);
      u16* oh = (s==3)? zh : zmh;
      u16* ol = (s==3)? zl : zml;
      switch (s){
        case 0: fused_gemm<1><<<NGRID,BDIM,0,stream>>>(hh, hl, W2h, W2l, b2, nullptr, tvec, step, s, oh, ol, z, zacc); break;
        case 1: fused_gemm<2><<<NGRID,BDIM,0,stream>>>(hh, hl, W2h, W2l, b2, nullptr, tvec, step, s, oh, ol, z, zacc); break;
        case 2: fused_gemm<3><<<NGRID,BDIM,0,stream>>>(hh, hl, W2h, W2l, b2, nullptr, tvec, step, s, oh, ol, z, zacc); break;
        case 3: fused_gemm<4><<<NGRID,BDIM,0,stream>>>(hh, hl, W2h, W2l, b2, nullptr, tvec, step, s, oh, ol, z, zacc); break;
      }
    }
  }
}